// Round 1
// baseline (1381.684 us; speedup 1.0000x reference)
//
#include <hip/hip_runtime.h>

namespace {

constexpr int kB = 4096;
constexpr int kT = 256;
constexpr int kLags = 32;
constexpr int kH = 128;
constexpr int kSteps = 255;   // 32 warmup + 223 AR steps
constexpr int kOut = 224;     // kT - kLags
constexpr int kMT = 16;       // batch rows per block
constexpr int kThreads = 256;
constexpr int kHPad = 132;    // padded h row stride (floats) to break bank conflicts

struct SMem {
    float wh[kH][kH];          // 64 KB, Wh[i][j], j contiguous
    float h[kMT][kHPad];       // hidden state, [m][i]
    float x0[kMT][kT];         // feature 0 for all steps (t<255 used)
    float x1w[kMT][kLags];     // feature 1 for warmup steps
    float wx0[kH];
    float wx1[kH];
    float bb[kH];
    float wd[kH];
    float pp[2 * kMT];         // per-col-half partial preds
};

union F4 { float4 v; float f[4]; };

__device__ __forceinline__ float fast_tanh(float x) {
    // tanh(x) = 1 - 2/(exp(2x)+1); exact saturation at +/-inf, ~1e-7 abs err
    float e = __expf(2.0f * x);
    return 1.0f - 2.0f * __builtin_amdgcn_rcpf(e + 1.0f);
}

__global__ __launch_bounds__(kThreads)
void arx_rnn_es_kernel(const float* __restrict__ inputs,
                       const float* __restrict__ Wx,
                       const float* __restrict__ Wh,
                       const float* __restrict__ bias,
                       const float* __restrict__ Wd,
                       const float* __restrict__ bd,
                       const float* __restrict__ alpha,
                       float* __restrict__ out) {
    __shared__ SMem sm;
    const int tid = threadIdx.x;
    const int b0 = blockIdx.x * kMT;

    // ---------------- one-time staging ----------------
    // Wh -> LDS (fp32, 16384 floats, float4 vectorized)
    for (int idx = tid; idx < kH * kH / 4; idx += kThreads) {
        ((float4*)&sm.wh[0][0])[idx] = ((const float4*)Wh)[idx];
    }
    for (int j = tid; j < kH; j += kThreads) {
        sm.wx0[j] = Wx[j];        // Wx[0][j]
        sm.wx1[j] = Wx[kH + j];   // Wx[1][j]
        sm.bb[j]  = bias[j];
        sm.wd[j]  = Wd[j];
    }
    // h0 = 0
    for (int idx = tid; idx < kMT * kHPad; idx += kThreads) {
        (&sm.h[0][0])[idx] = 0.0f;
    }
    // preload exogenous inputs: x0[m][t] = inputs[b][t][0]; x1w[m][t<32] = inputs[b][t][1]
    for (int idx = tid; idx < kMT * kT; idx += kThreads) {
        const int m = idx >> 8;
        const int t = idx & 255;
        if (t < kSteps) {
            float2 v = ((const float2*)inputs)[(size_t)(b0 + m) * kT + t];
            sm.x0[m][t] = v.x;
            if (t < kLags) sm.x1w[m][t] = v.y;
        }
    }
    const float av  = fminf(fmaxf(alpha[0], 0.0f), 1.0f);
    const float bdv = bd[0];
    __syncthreads();

    // ---------------- thread tile mapping ----------------
    const int lane = tid & 63;
    const int wv   = tid >> 6;       // wave 0..3
    const int cw   = wv & 1;         // column half (0: cols 0..63, 1: 64..127)
    const int rw   = wv >> 1;        // row group (0: rows 0..7, 1: rows 8..15)
    const int tn   = lane & 15;      // col sub-group
    const int rm   = lane >> 4;      // row quad 0..3
    const int jb   = cw * 64 + tn * 4;     // this thread's 4 cols: jb..jb+3
    const int m0   = rw * 8 + rm * 2;      // this thread's 2 rows: m0, m0+1
    const bool owner = (tn == 0) && (cw == 0);  // 8 threads own es state, 2 rows each

    float es0 = 0.0f, es1 = 0.0f;

    // ---------------- time loop ----------------
    for (int st = 0; st < kSteps; ++st) {
        // exogenous input (feature 0) — same index for warmup and AR phases
        const float x0a = sm.x0[m0][st];
        const float x0b = sm.x0[m0 + 1][st];
        // feature 1: warmup = inputs[:,:,1]; AR = previous pred (combine partials)
        float x1a, x1b;
        if (st < kLags) {
            x1a = sm.x1w[m0][st];
            x1b = sm.x1w[m0 + 1][st];
        } else {
            x1a = sm.pp[m0]     + sm.pp[kMT + m0]     + bdv;  // pred_{st-1}
            x1b = sm.pp[m0 + 1] + sm.pp[kMT + m0 + 1] + bdv;
        }
        // owner threads: finalize pred_{st-1} -> es, write output column st-32
        if (st >= kLags && owner) {
            if (st == kLags) { es0 = x1a; es1 = x1b; }   // first pred, un-smoothed
            else {
                es0 = av * x1a + (1.0f - av) * es0;
                es1 = av * x1b + (1.0f - av) * es1;
            }
            out[(size_t)(b0 + m0) * kOut + (st - kLags)]     = es0;
            out[(size_t)(b0 + m0 + 1) * kOut + (st - kLags)] = es1;
        }

        // ---- z = h @ Wh  (2 rows x 4 cols per thread, K=128)
        float a00 = 0.f, a01 = 0.f, a02 = 0.f, a03 = 0.f;
        float a10 = 0.f, a11 = 0.f, a12 = 0.f, a13 = 0.f;
        for (int i = 0; i < kH; i += 4) {
            F4 h0, h1, w0, w1, w2, w3;
            h0.v = *(const float4*)&sm.h[m0][i];
            h1.v = *(const float4*)&sm.h[m0 + 1][i];
            w0.v = *(const float4*)&sm.wh[i][jb];
            w1.v = *(const float4*)&sm.wh[i + 1][jb];
            w2.v = *(const float4*)&sm.wh[i + 2][jb];
            w3.v = *(const float4*)&sm.wh[i + 3][jb];

            a00 = fmaf(h0.f[0], w0.f[0], a00); a01 = fmaf(h0.f[0], w0.f[1], a01);
            a02 = fmaf(h0.f[0], w0.f[2], a02); a03 = fmaf(h0.f[0], w0.f[3], a03);
            a10 = fmaf(h1.f[0], w0.f[0], a10); a11 = fmaf(h1.f[0], w0.f[1], a11);
            a12 = fmaf(h1.f[0], w0.f[2], a12); a13 = fmaf(h1.f[0], w0.f[3], a13);

            a00 = fmaf(h0.f[1], w1.f[0], a00); a01 = fmaf(h0.f[1], w1.f[1], a01);
            a02 = fmaf(h0.f[1], w1.f[2], a02); a03 = fmaf(h0.f[1], w1.f[3], a03);
            a10 = fmaf(h1.f[1], w1.f[0], a10); a11 = fmaf(h1.f[1], w1.f[1], a11);
            a12 = fmaf(h1.f[1], w1.f[2], a12); a13 = fmaf(h1.f[1], w1.f[3], a13);

            a00 = fmaf(h0.f[2], w2.f[0], a00); a01 = fmaf(h0.f[2], w2.f[1], a01);
            a02 = fmaf(h0.f[2], w2.f[2], a02); a03 = fmaf(h0.f[2], w2.f[3], a03);
            a10 = fmaf(h1.f[2], w2.f[0], a10); a11 = fmaf(h1.f[2], w2.f[1], a11);
            a12 = fmaf(h1.f[2], w2.f[2], a12); a13 = fmaf(h1.f[2], w2.f[3], a13);

            a00 = fmaf(h0.f[3], w3.f[0], a00); a01 = fmaf(h0.f[3], w3.f[1], a01);
            a02 = fmaf(h0.f[3], w3.f[2], a02); a03 = fmaf(h0.f[3], w3.f[3], a03);
            a10 = fmaf(h1.f[3], w3.f[0], a10); a11 = fmaf(h1.f[3], w3.f[1], a11);
            a12 = fmaf(h1.f[3], w3.f[2], a12); a13 = fmaf(h1.f[3], w3.f[3], a13);
        }

        // ---- add x@Wx + b, tanh, pred partials
        F4 wxa, wxb, bv, wdv, hn0, hn1;
        wxa.v = *(const float4*)&sm.wx0[jb];
        wxb.v = *(const float4*)&sm.wx1[jb];
        bv.v  = *(const float4*)&sm.bb[jb];
        wdv.v = *(const float4*)&sm.wd[jb];

        float acc0[4] = {a00, a01, a02, a03};
        float acc1[4] = {a10, a11, a12, a13};
        float pp0 = 0.0f, pp1 = 0.0f;
#pragma unroll
        for (int c = 0; c < 4; ++c) {
            float z0 = acc0[c] + bv.f[c] + x0a * wxa.f[c] + x1a * wxb.f[c];
            float z1 = acc1[c] + bv.f[c] + x0b * wxa.f[c] + x1b * wxb.f[c];
            hn0.f[c] = fast_tanh(z0);
            hn1.f[c] = fast_tanh(z1);
            pp0 = fmaf(hn0.f[c], wdv.f[c], pp0);
            pp1 = fmaf(hn1.f[c], wdv.f[c], pp1);
        }

        __syncthreads();  // B1: all reads of sm.h / sm.pp for this step done

        *(float4*)&sm.h[m0][jb]     = hn0.v;
        *(float4*)&sm.h[m0 + 1][jb] = hn1.v;

        // reduce pred partials across the 16 col sub-groups (lane bits 0..3)
#pragma unroll
        for (int msk = 1; msk < 16; msk <<= 1) {
            pp0 += __shfl_xor(pp0, msk, 64);
            pp1 += __shfl_xor(pp1, msk, 64);
        }
        if (tn == 0) {
            sm.pp[cw * kMT + m0]     = pp0;
            sm.pp[cw * kMT + m0 + 1] = pp1;
        }

        __syncthreads();  // B2: new h / pp visible for next step
    }

    // ---------------- final output column (pred_254 -> es -> col 223) ----------------
    if (owner) {
        float p0 = sm.pp[m0]     + sm.pp[kMT + m0]     + bdv;
        float p1 = sm.pp[m0 + 1] + sm.pp[kMT + m0 + 1] + bdv;
        es0 = av * p0 + (1.0f - av) * es0;
        es1 = av * p1 + (1.0f - av) * es1;
        out[(size_t)(b0 + m0) * kOut + (kOut - 1)]     = es0;
        out[(size_t)(b0 + m0 + 1) * kOut + (kOut - 1)] = es1;
    }
}

}  // namespace

extern "C" void kernel_launch(void* const* d_in, const int* in_sizes, int n_in,
                              void* d_out, int out_size, void* d_ws, size_t ws_size,
                              hipStream_t stream) {
    const float* inputs = (const float*)d_in[0];
    const float* Wx     = (const float*)d_in[1];
    const float* Wh     = (const float*)d_in[2];
    const float* bias   = (const float*)d_in[3];
    const float* Wd     = (const float*)d_in[4];
    const float* bd     = (const float*)d_in[5];
    const float* alpha  = (const float*)d_in[6];
    // d_in[7] = lags (compile-time constant 32 here)

    arx_rnn_es_kernel<<<kB / kMT, kThreads, 0, stream>>>(
        inputs, Wx, Wh, bias, Wd, bd, alpha, (float*)d_out);
}

// Round 2
// 347.253 us; speedup vs baseline: 3.9789x; 3.9789x over previous
//
#include <hip/hip_runtime.h>

namespace {

constexpr int kB = 4096;
constexpr int kT = 256;
constexpr int kLags = 32;
constexpr int kH = 128;
constexpr int kSteps = 255;   // 32 warmup + 223 AR steps
constexpr int kOut = 224;     // kT - kLags
constexpr int kMT = 16;       // batch rows per block
constexpr int kThreads = 256;
constexpr int kHS = 136;      // bf16 row stride for h arrays (272 B, 16B-aligned)

typedef __attribute__((ext_vector_type(8))) short short8;
typedef __attribute__((ext_vector_type(4))) float f32x4;

struct __align__(16) SMem {
    unsigned short hhi[kMT][kHS];   // h high bf16, row-major (A-frag friendly)
    unsigned short hlo[kMT][kHS];   // h low  bf16
    float x0T[kT][kMT];             // feature 0, transposed [t][m]
    float x1wT[kLags][kMT];         // feature 1 warmup, transposed
    float ppT[4][kMT];              // per-wave pred partials [wave][m]
};

__device__ __forceinline__ unsigned short bf16_rne(float f) {
    unsigned u = __builtin_bit_cast(unsigned, f);
    u += 0x7FFFu + ((u >> 16) & 1u);
    return (unsigned short)(u >> 16);
}
__device__ __forceinline__ float bf16_f32(unsigned short h) {
    unsigned u = ((unsigned)h) << 16;
    return __builtin_bit_cast(float, u);
}
__device__ __forceinline__ float fast_tanh(float x) {
    float e = __expf(2.0f * x);
    return 1.0f - 2.0f * __builtin_amdgcn_rcpf(e + 1.0f);
}

__global__ __launch_bounds__(kThreads)
void arx_rnn_es_kernel(const float* __restrict__ inputs,
                       const float* __restrict__ Wx,
                       const float* __restrict__ Wh,
                       const float* __restrict__ bias,
                       const float* __restrict__ Wd,
                       const float* __restrict__ bd,
                       const float* __restrict__ alpha,
                       float* __restrict__ out) {
    __shared__ SMem sm;
    const int tid  = threadIdx.x;
    const int b0   = blockIdx.x * kMT;
    const int lane = tid & 63;
    const int w    = tid >> 6;        // wave 0..3, owns cols 32w..32w+31
    const int n    = lane & 15;
    const int quad = lane >> 4;
    const int m0   = 4 * quad;        // this lane's C-rows m0..m0+3
    const int m    = n;               // this lane's A-frag row

    // ---------------- one-time staging ----------------
    for (int idx = tid; idx < kMT * kT; idx += kThreads) {
        const int mm = idx >> 8;
        const int t  = idx & 255;
        float2 v = ((const float2*)inputs)[(size_t)(b0 + mm) * kT + t];
        sm.x0T[t][mm] = v.x;
        if (t < kLags) sm.x1wT[t][mm] = v.y;
    }
    for (int idx = tid; idx < kMT * kHS; idx += kThreads) {
        ((unsigned short*)sm.hhi)[idx] = 0;
        ((unsigned short*)sm.hlo)[idx] = 0;
    }

    // per-lane column constants (cols col0 and col1 of this lane)
    const int col0 = w * 32 + n;
    const int col1 = col0 + 16;
    float b_c[2], wx0c[2], wx1c[2], wdc[2];
    b_c[0]  = bias[col0];     b_c[1]  = bias[col1];
    wx0c[0] = Wx[col0];       wx0c[1] = Wx[col1];
    wx1c[0] = Wx[kH + col0];  wx1c[1] = Wx[kH + col1];
    wdc[0]  = Wd[col0];       wdc[1]  = Wd[col1];
    const float av  = fminf(fmaxf(alpha[0], 0.0f), 1.0f);
    const float bdv = bd[0];

    // B-fragments: Wh split hi/lo bf16, resident in registers for all 255 steps.
    // B-frag layout: lane (quad,n) holds B[k = c*32 + quad*8 + j][col], j=0..7
    short8 bhi[2][4], blo[2][4];
    for (int t = 0; t < 2; ++t) {
        const int col = t ? col1 : col0;
        for (int c = 0; c < 4; ++c) {
            for (int j = 0; j < 8; ++j) {
                const int k = c * 32 + quad * 8 + j;
                float wv = Wh[(size_t)k * kH + col];
                unsigned short hi = bf16_rne(wv);
                unsigned short lo = bf16_rne(wv - bf16_f32(hi));
                bhi[t][c][j] = (short)hi;
                blo[t][c][j] = (short)lo;
            }
        }
    }
    __syncthreads();

    f32x4 es = {0.f, 0.f, 0.f, 0.f};

    // ---------------- time loop ----------------
#pragma unroll 1
    for (int st = 0; st < kSteps; ++st) {
        // x0[m] for this lane's 4 C-rows (broadcast across the 16 n-lanes of a quad)
        f32x4 x0v = *(const f32x4*)&sm.x0T[st][m0];
        f32x4 x1v;
        if (st < kLags) {
            x1v = *(const f32x4*)&sm.x1wT[st][m0];
        } else {
            f32x4 p0 = *(const f32x4*)&sm.ppT[0][m0];
            f32x4 p1 = *(const f32x4*)&sm.ppT[1][m0];
            f32x4 p2 = *(const f32x4*)&sm.ppT[2][m0];
            f32x4 p3 = *(const f32x4*)&sm.ppT[3][m0];
            f32x4 s = (p0 + p1) + (p2 + p3);
            x1v[0] = s[0] + bdv; x1v[1] = s[1] + bdv;
            x1v[2] = s[2] + bdv; x1v[3] = s[3] + bdv;
        }
        // ES owners: wave 0, n==0 lanes (one per quad) own rows m0..m0+3
        if (st >= kLags && w == 0 && n == 0) {
            if (st == kLags) {
                es = x1v;   // first prediction appended un-smoothed
            } else {
#pragma unroll
                for (int r = 0; r < 4; ++r)
                    es[r] = av * x1v[r] + (1.0f - av) * es[r];
            }
#pragma unroll
            for (int r = 0; r < 4; ++r)
                out[(size_t)(b0 + m0 + r) * kOut + (st - kLags)] = es[r];
        }

        // ---- z = h @ Wh via MFMA, split-bf16 (hh + hl + lh products)
        f32x4 acc0 = {0.f, 0.f, 0.f, 0.f};
        f32x4 acc1 = {0.f, 0.f, 0.f, 0.f};
#pragma unroll
        for (int c = 0; c < 4; ++c) {
            const int k0 = c * 32 + quad * 8;
            short8 ah = *(const short8*)&sm.hhi[m][k0];
            short8 al = *(const short8*)&sm.hlo[m][k0];
            acc0 = __builtin_amdgcn_mfma_f32_16x16x32_bf16(ah, bhi[0][c], acc0, 0, 0, 0);
            acc1 = __builtin_amdgcn_mfma_f32_16x16x32_bf16(ah, bhi[1][c], acc1, 0, 0, 0);
            acc0 = __builtin_amdgcn_mfma_f32_16x16x32_bf16(ah, blo[0][c], acc0, 0, 0, 0);
            acc1 = __builtin_amdgcn_mfma_f32_16x16x32_bf16(ah, blo[1][c], acc1, 0, 0, 0);
            acc0 = __builtin_amdgcn_mfma_f32_16x16x32_bf16(al, bhi[0][c], acc0, 0, 0, 0);
            acc1 = __builtin_amdgcn_mfma_f32_16x16x32_bf16(al, bhi[1][c], acc1, 0, 0, 0);
        }

        // ---- epilogue: z -> tanh -> h (split bf16) + pred partials
        unsigned short hhis[2][4], hlos[2][4];
        float ppr[4] = {0.f, 0.f, 0.f, 0.f};
#pragma unroll
        for (int t = 0; t < 2; ++t) {
            f32x4 a = t ? acc1 : acc0;
#pragma unroll
            for (int r = 0; r < 4; ++r) {
                float z  = a[r] + b_c[t] + x0v[r] * wx0c[t] + x1v[r] * wx1c[t];
                float hf = fast_tanh(z);
                ppr[r]   = fmaf(hf, wdc[t], ppr[r]);
                unsigned short hi = bf16_rne(hf);
                hhis[t][r] = hi;
                hlos[t][r] = bf16_rne(hf - bf16_f32(hi));
            }
        }

        __syncthreads();  // B1: all A-frag / ppT reads for this step complete

        // write new h (C layout: row m0+r, col = this lane's col0/col1)
#pragma unroll
        for (int t = 0; t < 2; ++t) {
            const int col = t ? col1 : col0;
#pragma unroll
            for (int r = 0; r < 4; ++r) {
                sm.hhi[m0 + r][col] = hhis[t][r];
                sm.hlo[m0 + r][col] = hlos[t][r];
            }
        }
        // reduce pred partials over this wave's 16 n-lanes
#pragma unroll
        for (int msk = 1; msk < 16; msk <<= 1) {
#pragma unroll
            for (int r = 0; r < 4; ++r)
                ppr[r] += __shfl_xor(ppr[r], msk, 64);
        }
        if (n == 0) {
            f32x4 pv = {ppr[0], ppr[1], ppr[2], ppr[3]};
            *(f32x4*)&sm.ppT[w][m0] = pv;
        }

        __syncthreads();  // B2: new h / pp visible for next step
    }

    // ---------------- final output column (pred_254 -> es -> col 223) ----------------
    if (w == 0 && n == 0) {
        f32x4 p0 = *(const f32x4*)&sm.ppT[0][m0];
        f32x4 p1 = *(const f32x4*)&sm.ppT[1][m0];
        f32x4 p2 = *(const f32x4*)&sm.ppT[2][m0];
        f32x4 p3 = *(const f32x4*)&sm.ppT[3][m0];
        f32x4 s = (p0 + p1) + (p2 + p3);
#pragma unroll
        for (int r = 0; r < 4; ++r) {
            float p = s[r] + bdv;
            es[r] = av * p + (1.0f - av) * es[r];
            out[(size_t)(b0 + m0 + r) * kOut + (kOut - 1)] = es[r];
        }
    }
}

}  // namespace

extern "C" void kernel_launch(void* const* d_in, const int* in_sizes, int n_in,
                              void* d_out, int out_size, void* d_ws, size_t ws_size,
                              hipStream_t stream) {
    const float* inputs = (const float*)d_in[0];
    const float* Wx     = (const float*)d_in[1];
    const float* Wh     = (const float*)d_in[2];
    const float* bias   = (const float*)d_in[3];
    const float* Wd     = (const float*)d_in[4];
    const float* bd     = (const float*)d_in[5];
    const float* alpha  = (const float*)d_in[6];
    // d_in[7] = lags (compile-time constant 32 here)

    arx_rnn_es_kernel<<<kB / kMT, kThreads, 0, stream>>>(
        inputs, Wx, Wh, bias, Wd, bd, alpha, (float*)d_out);
}

// Round 3
// 322.600 us; speedup vs baseline: 4.2830x; 1.0764x over previous
//
#include <hip/hip_runtime.h>

namespace {

constexpr int kB = 4096;
constexpr int kT = 256;
constexpr int kLags = 32;
constexpr int kH = 128;
constexpr int kSteps = 255;   // 32 warmup + 223 AR steps
constexpr int kOut = 224;     // kT - kLags
constexpr int kMT = 16;       // batch rows per block
constexpr int kThreads = 512; // 8 waves; wave w owns cols 16w..16w+15
constexpr int kHS = 136;      // bf16 row stride (272 B, 16B-aligned)

typedef __attribute__((ext_vector_type(8))) short short8;
typedef __attribute__((ext_vector_type(4))) float f32x4;

struct __align__(16) SMem {
    unsigned short hhi[2][kMT][kHS];  // double-buffered h, high bf16
    unsigned short hlo[2][kMT][kHS];  // double-buffered h, low bf16
    float x0T[kT][kMT];               // feature 0, transposed [t][m]
    float x1wT[kLags][kMT];           // feature 1 warmup, transposed
    float ppT[2][kMT][8];             // pred wave-partials, [parity][row][wave]
};

__device__ __forceinline__ unsigned short bf16_rne(float f) {
    unsigned u = __builtin_bit_cast(unsigned, f);
    u += 0x7FFFu + ((u >> 16) & 1u);
    return (unsigned short)(u >> 16);
}
__device__ __forceinline__ float bf16_f32(unsigned short h) {
    unsigned u = ((unsigned)h) << 16;
    return __builtin_bit_cast(float, u);
}
__device__ __forceinline__ float fast_tanh(float x) {
    float e = __expf(2.0f * x);
    return 1.0f - 2.0f * __builtin_amdgcn_rcpf(e + 1.0f);
}

__global__ __launch_bounds__(kThreads, 2)
void arx_rnn_es_kernel(const float* __restrict__ inputs,
                       const float* __restrict__ Wx,
                       const float* __restrict__ Wh,
                       const float* __restrict__ bias,
                       const float* __restrict__ Wd,
                       const float* __restrict__ bd,
                       const float* __restrict__ alpha,
                       float* __restrict__ out) {
    __shared__ SMem sm;
    const int tid  = threadIdx.x;
    const int b0   = blockIdx.x * kMT;
    const int lane = tid & 63;
    const int w    = tid >> 6;        // wave 0..7
    const int n    = lane & 15;
    const int quad = lane >> 4;
    const int m0   = 4 * quad;        // C-rows m0..m0+3

    // ---------------- one-time staging ----------------
    for (int idx = tid; idx < kMT * kT; idx += kThreads) {
        const int mm = idx >> 8;
        const int t  = idx & 255;
        float2 v = ((const float2*)inputs)[(size_t)(b0 + mm) * kT + t];
        sm.x0T[t][mm] = v.x;
        if (t < kLags) sm.x1wT[t][mm] = v.y;
    }
    for (int idx = tid; idx < kMT * kHS; idx += kThreads) {
        ((unsigned short*)sm.hhi[0])[idx] = 0;
        ((unsigned short*)sm.hlo[0])[idx] = 0;
    }

    // per-lane column constants
    const int col = w * 16 + n;
    const float wx0c = Wx[col];
    const float wx1c = Wx[kH + col];
    const float b_c  = bias[col];
    const float wdc  = Wd[col];
    const float av   = fminf(fmaxf(alpha[0], 0.0f), 1.0f);
    const float bdv  = bd[0];
    const float bp_c = b_c + bdv * wx1c;   // folded bias for AR steps

    // B-fragments in registers for all 255 steps:
    //   whh/whl: Wh  split hi/lo (warmup)
    //   ahh/ahl: Wh' = Wh + Wd*Wx1^T split hi/lo (AR, pred feedback folded in)
    short8 whh[4], whl[4], ahh[4], ahl[4];
    for (int c = 0; c < 4; ++c) {
        for (int j = 0; j < 8; ++j) {
            const int k = c * 32 + quad * 8 + j;
            float base = Wh[(size_t)k * kH + col];
            unsigned short h1 = bf16_rne(base);
            whh[c][j] = (short)h1;
            whl[c][j] = (short)bf16_rne(base - bf16_f32(h1));
            float fold = fmaf(Wd[k], wx1c, base);
            unsigned short h2 = bf16_rne(fold);
            ahh[c][j] = (short)h2;
            ahl[c][j] = (short)bf16_rne(fold - bf16_f32(h2));
        }
    }
    __syncthreads();

    int p = 0;

    // ---------------- warmup: st = 0..31 ----------------
#pragma unroll 1
    for (int st = 0; st < kLags; ++st) {
        f32x4 x0v = *(const f32x4*)&sm.x0T[st][m0];
        f32x4 x1v = *(const f32x4*)&sm.x1wT[st][m0];

        f32x4 a0 = {0.f, 0.f, 0.f, 0.f};
        f32x4 a1 = {0.f, 0.f, 0.f, 0.f};
        f32x4 a2 = {0.f, 0.f, 0.f, 0.f};
#pragma unroll
        for (int c = 0; c < 4; ++c) {
            const int k0 = c * 32 + quad * 8;
            short8 ah = *(const short8*)&sm.hhi[p][n][k0];
            short8 al = *(const short8*)&sm.hlo[p][n][k0];
            a0 = __builtin_amdgcn_mfma_f32_16x16x32_bf16(ah, whh[c], a0, 0, 0, 0);
            a1 = __builtin_amdgcn_mfma_f32_16x16x32_bf16(ah, whl[c], a1, 0, 0, 0);
            a2 = __builtin_amdgcn_mfma_f32_16x16x32_bf16(al, whh[c], a2, 0, 0, 0);
        }
        f32x4 acc = (a0 + a1) + a2;

        unsigned short hhis[4], hlos[4];
        float ppr[4];
#pragma unroll
        for (int r = 0; r < 4; ++r) {
            float z  = acc[r] + b_c + x0v[r] * wx0c + x1v[r] * wx1c;
            float hf = fast_tanh(z);
            ppr[r] = hf * wdc;
            unsigned short hi = bf16_rne(hf);
            hhis[r] = hi;
            hlos[r] = bf16_rne(hf - bf16_f32(hi));
        }
#pragma unroll
        for (int r = 0; r < 4; ++r) {
            sm.hhi[1 - p][m0 + r][col] = hhis[r];
            sm.hlo[1 - p][m0 + r][col] = hlos[r];
        }
#pragma unroll
        for (int msk = 1; msk < 16; msk <<= 1) {
#pragma unroll
            for (int r = 0; r < 4; ++r) ppr[r] += __shfl_xor(ppr[r], msk, 64);
        }
        if (n == 0) {
#pragma unroll
            for (int r = 0; r < 4; ++r) sm.ppT[st & 1][m0 + r][w] = ppr[r];
        }
        __syncthreads();
        p ^= 1;
    }

    // ---------------- AR: st = 32..254, pred folded into Wh' ----------------
    float es = 0.0f;   // wave 0, lane r<16 carries es for batch row r
#pragma unroll 1
    for (int st = kLags; st < kSteps; ++st) {
        // deferred ES scan — off the h critical path
        if (w == 0 && lane < 16) {
            f32x4 q0 = *(const f32x4*)&sm.ppT[(st - 1) & 1][lane][0];
            f32x4 q1 = *(const f32x4*)&sm.ppT[(st - 1) & 1][lane][4];
            float pred = (((q0[0] + q0[1]) + (q0[2] + q0[3])) +
                          ((q1[0] + q1[1]) + (q1[2] + q1[3]))) + bdv;
            es = (st == kLags) ? pred : (av * pred + (1.0f - av) * es);
            out[(size_t)(b0 + lane) * kOut + (st - kLags)] = es;
        }

        f32x4 x0v = *(const f32x4*)&sm.x0T[st][m0];

        f32x4 a0 = {0.f, 0.f, 0.f, 0.f};
        f32x4 a1 = {0.f, 0.f, 0.f, 0.f};
        f32x4 a2 = {0.f, 0.f, 0.f, 0.f};
#pragma unroll
        for (int c = 0; c < 4; ++c) {
            const int k0 = c * 32 + quad * 8;
            short8 ah = *(const short8*)&sm.hhi[p][n][k0];
            short8 al = *(const short8*)&sm.hlo[p][n][k0];
            a0 = __builtin_amdgcn_mfma_f32_16x16x32_bf16(ah, ahh[c], a0, 0, 0, 0);
            a1 = __builtin_amdgcn_mfma_f32_16x16x32_bf16(ah, ahl[c], a1, 0, 0, 0);
            a2 = __builtin_amdgcn_mfma_f32_16x16x32_bf16(al, ahh[c], a2, 0, 0, 0);
        }
        f32x4 acc = (a0 + a1) + a2;

        unsigned short hhis[4], hlos[4];
        float ppr[4];
#pragma unroll
        for (int r = 0; r < 4; ++r) {
            float z  = acc[r] + bp_c + x0v[r] * wx0c;
            float hf = fast_tanh(z);
            ppr[r] = hf * wdc;
            unsigned short hi = bf16_rne(hf);
            hhis[r] = hi;
            hlos[r] = bf16_rne(hf - bf16_f32(hi));
        }
#pragma unroll
        for (int r = 0; r < 4; ++r) {
            sm.hhi[1 - p][m0 + r][col] = hhis[r];
            sm.hlo[1 - p][m0 + r][col] = hlos[r];
        }
#pragma unroll
        for (int msk = 1; msk < 16; msk <<= 1) {
#pragma unroll
            for (int r = 0; r < 4; ++r) ppr[r] += __shfl_xor(ppr[r], msk, 64);
        }
        if (n == 0) {
#pragma unroll
            for (int r = 0; r < 4; ++r) sm.ppT[st & 1][m0 + r][w] = ppr[r];
        }
        __syncthreads();
        p ^= 1;
    }

    // ---------------- final output column (pred_254 -> es -> col 223) ----------------
    if (w == 0 && lane < 16) {
        const int par = (kSteps - 1) & 1;
        f32x4 q0 = *(const f32x4*)&sm.ppT[par][lane][0];
        f32x4 q1 = *(const f32x4*)&sm.ppT[par][lane][4];
        float pred = (((q0[0] + q0[1]) + (q0[2] + q0[3])) +
                      ((q1[0] + q1[1]) + (q1[2] + q1[3]))) + bdv;
        es = av * pred + (1.0f - av) * es;
        out[(size_t)(b0 + lane) * kOut + (kOut - 1)] = es;
    }
}

}  // namespace

extern "C" void kernel_launch(void* const* d_in, const int* in_sizes, int n_in,
                              void* d_out, int out_size, void* d_ws, size_t ws_size,
                              hipStream_t stream) {
    const float* inputs = (const float*)d_in[0];
    const float* Wx     = (const float*)d_in[1];
    const float* Wh     = (const float*)d_in[2];
    const float* bias   = (const float*)d_in[3];
    const float* Wd     = (const float*)d_in[4];
    const float* bd     = (const float*)d_in[5];
    const float* alpha  = (const float*)d_in[6];
    // d_in[7] = lags (compile-time constant 32 here)

    arx_rnn_es_kernel<<<kB / kMT, kThreads, 0, stream>>>(
        inputs, Wx, Wh, bias, Wd, bd, alpha, (float*)d_out);
}

// Round 4
// 284.257 us; speedup vs baseline: 4.8607x; 1.1349x over previous
//
#include <hip/hip_runtime.h>

namespace {

constexpr int kB = 4096;
constexpr int kT = 256;
constexpr int kLags = 32;
constexpr int kH = 128;
constexpr int kSteps = 255;   // 32 warmup + 223 AR steps
constexpr int kOut = 224;     // kT - kLags
constexpr int kMT = 16;       // batch rows per block
constexpr int kThreads = 256; // 4 waves; wave w owns cols 32w..32w+31
// h row stride in u32. 140*4=560 B (16B-aligned rows); (140/4)=35 odd =>
// A-frag read start banks are uniform over the 64 lanes (no extra conflicts).
constexpr int kHW = 140;

typedef __attribute__((ext_vector_type(8))) short short8;
typedef __attribute__((ext_vector_type(4))) float f32x4;

union AB { short8 s; unsigned u[4]; };

struct __align__(16) SMem {
    unsigned h32[2][kMT][kHW];   // packed h: (bf16_hi << 16) | bf16_lo, double-buffered
    float x0T[kT][kMT];          // feature 0, transposed [t][m]
    float x1wT[kLags][kMT];      // feature 1 warmup, transposed
    float pp[2][4][20];          // pred partials [parity][wave][row(16) pad 20]
};

__device__ __forceinline__ unsigned short bf16_rne(float f) {
    unsigned u = __builtin_bit_cast(unsigned, f);
    u += 0x7FFFu + ((u >> 16) & 1u);
    return (unsigned short)(u >> 16);
}
__device__ __forceinline__ float bf16_f32(unsigned short h) {
    unsigned u = ((unsigned)h) << 16;
    return __builtin_bit_cast(float, u);
}
__device__ __forceinline__ float fast_tanh(float x) {
    float e = __expf(2.0f * x);
    return 1.0f - 2.0f * __builtin_amdgcn_rcpf(e + 1.0f);
}
// pack h -> (bf16_rne_hi << 16) | trunc_bf16(h - hi)
__device__ __forceinline__ unsigned pack_h(float hf) {
    unsigned ub = __builtin_bit_cast(unsigned, hf);
    unsigned rb = (ub + (0x7FFFu + ((ub >> 16) & 1u))) & 0xFFFF0000u;
    float d = hf - __builtin_bit_cast(float, rb);
    return rb | (__builtin_bit_cast(unsigned, d) >> 16);
}

// VALU-only 16-lane reduce (no DS pipe): quad_perm xor1, xor2, then row_ror 4, 8.
#define DPP_ADD(v, CTRL)                                                        \
    {                                                                           \
        int _t = __builtin_amdgcn_update_dpp(0, __builtin_bit_cast(int, (v)),   \
                                             (CTRL), 0xF, 0xF, true);           \
        (v) += __builtin_bit_cast(float, _t);                                   \
    }
#define DPP_REDUCE16(v)                                                         \
    {                                                                           \
        DPP_ADD(v, 0xB1);  /* quad_perm [1,0,3,2] : xor 1 */                    \
        DPP_ADD(v, 0x4E);  /* quad_perm [2,3,0,1] : xor 2 */                    \
        DPP_ADD(v, 0x124); /* row_ror:4 */                                      \
        DPP_ADD(v, 0x128); /* row_ror:8 */                                      \
    }

__global__ __launch_bounds__(kThreads)
void arx_rnn_es_kernel(const float* __restrict__ inputs,
                       const float* __restrict__ Wx,
                       const float* __restrict__ Wh,
                       const float* __restrict__ bias,
                       const float* __restrict__ Wd,
                       const float* __restrict__ bd,
                       const float* __restrict__ alpha,
                       float* __restrict__ out) {
    __shared__ SMem sm;
    const int tid  = threadIdx.x;
    const int b0   = blockIdx.x * kMT;
    const int lane = tid & 63;
    const int w    = tid >> 6;        // wave 0..3
    const int n    = lane & 15;
    const int q    = lane >> 4;       // quad
    const int m0   = 4 * q;           // C-rows m0..m0+3

    // ---------------- one-time staging ----------------
    for (int idx = tid; idx < kMT * kT; idx += kThreads) {
        const int mm = idx >> 8;
        const int t  = idx & 255;
        float2 v = ((const float2*)inputs)[(size_t)(b0 + mm) * kT + t];
        sm.x0T[t][mm] = v.x;
        if (t < kLags) sm.x1wT[t][mm] = v.y;
    }
    for (int idx = tid; idx < kMT * kHW; idx += kThreads) ((unsigned*)sm.h32[0])[idx] = 0;
    for (int idx = tid; idx < 2 * 4 * 20; idx += kThreads) ((float*)sm.pp)[idx] = 0.0f;

    // per-lane column constants (2 tiles: cols col0, col0+16)
    const int col0 = w * 32 + n;
    float b_c[2], wx0c[2], wx1c[2], wdc[2], bp_c[2];
    const float av  = fminf(fmaxf(alpha[0], 0.0f), 1.0f);
    const float bdv = bd[0];
#pragma unroll
    for (int t = 0; t < 2; ++t) {
        const int col = col0 + t * 16;
        b_c[t]  = bias[col];
        wx0c[t] = Wx[col];
        wx1c[t] = Wx[kH + col];
        wdc[t]  = Wd[col];
        bp_c[t] = b_c[t] + bdv * wx1c[t];   // folded bias for AR steps
    }

    // B-fragments: Wh' = Wh + Wd*Wx1^T, split hi/lo bf16, register-resident.
    // Used for BOTH phases (warmup corrects via x1_eff = x1 - h.Wd).
    short8 bhh[2][4], bhl[2][4];
#pragma unroll
    for (int t = 0; t < 2; ++t) {
        const int col = col0 + t * 16;
#pragma unroll
        for (int c = 0; c < 4; ++c) {
#pragma unroll
            for (int j = 0; j < 8; ++j) {
                const int k = c * 32 + q * 8 + j;
                float wv = fmaf(Wd[k], wx1c[t], Wh[(size_t)k * kH + col]);
                unsigned short hi = bf16_rne(wv);
                bhh[t][c][j] = (short)hi;
                bhl[t][c][j] = (short)bf16_rne(wv - bf16_f32(hi));
            }
        }
    }
    __syncthreads();

    int p = 0;
    float es = 0.0f;   // wave 0, lane r<16 carries es for batch row r

    // ---------------- warmup: st = 0..31 ----------------
#pragma unroll 1
    for (int st = 0; st < kLags; ++st) {
        const int par_r = (st + 1) & 1;  // parity written by previous step
        f32x4 x0v  = *(const f32x4*)&sm.x0T[st][m0];
        f32x4 x1wv = *(const f32x4*)&sm.x1wT[st][m0];
        // p~ = h.Wd for this lane's 4 rows (sum of 4 wave partials)
        f32x4 P = *(const f32x4*)&sm.pp[par_r][0][m0];
        P += *(const f32x4*)&sm.pp[par_r][1][m0];
        P += *(const f32x4*)&sm.pp[par_r][2][m0];
        P += *(const f32x4*)&sm.pp[par_r][3][m0];
        f32x4 x1e = x1wv - P;   // x1_eff: cancels the folded Wd*wx1 term

        // ---- MFMA: z = h @ Wh'
        f32x4 A0[2], A1[2], A2[2];
#pragma unroll
        for (int t = 0; t < 2; ++t) { A0[t] = {0,0,0,0}; A1[t] = {0,0,0,0}; A2[t] = {0,0,0,0}; }
#pragma unroll
        for (int c = 0; c < 4; ++c) {
            const unsigned* src = &sm.h32[p][n][c * 32 + 8 * q];
            uint4 ua = *(const uint4*)src;
            uint4 ub = *(const uint4*)(src + 4);
            AB ah, al;
            ah.u[0] = __builtin_amdgcn_perm(ua.y, ua.x, 0x07060302u);
            ah.u[1] = __builtin_amdgcn_perm(ua.w, ua.z, 0x07060302u);
            ah.u[2] = __builtin_amdgcn_perm(ub.y, ub.x, 0x07060302u);
            ah.u[3] = __builtin_amdgcn_perm(ub.w, ub.z, 0x07060302u);
            al.u[0] = __builtin_amdgcn_perm(ua.y, ua.x, 0x05040100u);
            al.u[1] = __builtin_amdgcn_perm(ua.w, ua.z, 0x05040100u);
            al.u[2] = __builtin_amdgcn_perm(ub.y, ub.x, 0x05040100u);
            al.u[3] = __builtin_amdgcn_perm(ub.w, ub.z, 0x05040100u);
#pragma unroll
            for (int t = 0; t < 2; ++t) {
                A0[t] = __builtin_amdgcn_mfma_f32_16x16x32_bf16(ah.s, bhh[t][c], A0[t], 0, 0, 0);
                A1[t] = __builtin_amdgcn_mfma_f32_16x16x32_bf16(ah.s, bhl[t][c], A1[t], 0, 0, 0);
                A2[t] = __builtin_amdgcn_mfma_f32_16x16x32_bf16(al.s, bhh[t][c], A2[t], 0, 0, 0);
            }
        }

        // ---- epilogue
        unsigned pk[2][4];
        float ppr[4] = {0.f, 0.f, 0.f, 0.f};
#pragma unroll
        for (int t = 0; t < 2; ++t) {
            f32x4 acc = (A0[t] + A1[t]) + A2[t];
#pragma unroll
            for (int r = 0; r < 4; ++r) {
                float z  = acc[r] + b_c[t] + x0v[r] * wx0c[t] + x1e[r] * wx1c[t];
                float hf = fast_tanh(z);
                ppr[r]   = fmaf(hf, wdc[t], ppr[r]);
                pk[t][r] = pack_h(hf);
            }
        }
#pragma unroll
        for (int t = 0; t < 2; ++t)
#pragma unroll
            for (int r = 0; r < 4; ++r)
                sm.h32[1 - p][m0 + r][col0 + t * 16] = pk[t][r];

#pragma unroll
        for (int r = 0; r < 4; ++r) DPP_REDUCE16(ppr[r]);
        {   // lanes n<4 write one row-partial each
            float v01 = (n & 1) ? ppr[1] : ppr[0];
            float v23 = (n & 1) ? ppr[3] : ppr[2];
            float vv  = (n & 2) ? v23 : v01;
            if (n < 4) sm.pp[st & 1][w][m0 + n] = vv;
        }
        __syncthreads();
        p ^= 1;
    }

    // ---------------- AR: st = 32..254 (pred folded into Wh') ----------------
#pragma unroll 1
    for (int st = kLags; st < kSteps; ++st) {
        const int par_r = (st + 1) & 1;
        // deferred ES scan — only the 16 owner lanes touch pp
        if (w == 0 && lane < 16) {
            float pr = ((sm.pp[par_r][0][lane] + sm.pp[par_r][1][lane]) +
                        (sm.pp[par_r][2][lane] + sm.pp[par_r][3][lane])) + bdv;
            es = (st == kLags) ? pr : (av * pr + (1.0f - av) * es);
            out[(size_t)(b0 + lane) * kOut + (st - kLags)] = es;
        }

        f32x4 x0v = *(const f32x4*)&sm.x0T[st][m0];

        f32x4 A0[2], A1[2], A2[2];
#pragma unroll
        for (int t = 0; t < 2; ++t) { A0[t] = {0,0,0,0}; A1[t] = {0,0,0,0}; A2[t] = {0,0,0,0}; }
#pragma unroll
        for (int c = 0; c < 4; ++c) {
            const unsigned* src = &sm.h32[p][n][c * 32 + 8 * q];
            uint4 ua = *(const uint4*)src;
            uint4 ub = *(const uint4*)(src + 4);
            AB ah, al;
            ah.u[0] = __builtin_amdgcn_perm(ua.y, ua.x, 0x07060302u);
            ah.u[1] = __builtin_amdgcn_perm(ua.w, ua.z, 0x07060302u);
            ah.u[2] = __builtin_amdgcn_perm(ub.y, ub.x, 0x07060302u);
            ah.u[3] = __builtin_amdgcn_perm(ub.w, ub.z, 0x07060302u);
            al.u[0] = __builtin_amdgcn_perm(ua.y, ua.x, 0x05040100u);
            al.u[1] = __builtin_amdgcn_perm(ua.w, ua.z, 0x05040100u);
            al.u[2] = __builtin_amdgcn_perm(ub.y, ub.x, 0x05040100u);
            al.u[3] = __builtin_amdgcn_perm(ub.w, ub.z, 0x05040100u);
#pragma unroll
            for (int t = 0; t < 2; ++t) {
                A0[t] = __builtin_amdgcn_mfma_f32_16x16x32_bf16(ah.s, bhh[t][c], A0[t], 0, 0, 0);
                A1[t] = __builtin_amdgcn_mfma_f32_16x16x32_bf16(ah.s, bhl[t][c], A1[t], 0, 0, 0);
                A2[t] = __builtin_amdgcn_mfma_f32_16x16x32_bf16(al.s, bhh[t][c], A2[t], 0, 0, 0);
            }
        }

        unsigned pk[2][4];
        float ppr[4] = {0.f, 0.f, 0.f, 0.f};
#pragma unroll
        for (int t = 0; t < 2; ++t) {
            f32x4 acc = (A0[t] + A1[t]) + A2[t];
#pragma unroll
            for (int r = 0; r < 4; ++r) {
                float z  = acc[r] + bp_c[t] + x0v[r] * wx0c[t];
                float hf = fast_tanh(z);
                ppr[r]   = fmaf(hf, wdc[t], ppr[r]);
                pk[t][r] = pack_h(hf);
            }
        }
#pragma unroll
        for (int t = 0; t < 2; ++t)
#pragma unroll
            for (int r = 0; r < 4; ++r)
                sm.h32[1 - p][m0 + r][col0 + t * 16] = pk[t][r];

#pragma unroll
        for (int r = 0; r < 4; ++r) DPP_REDUCE16(ppr[r]);
        {
            float v01 = (n & 1) ? ppr[1] : ppr[0];
            float v23 = (n & 1) ? ppr[3] : ppr[2];
            float vv  = (n & 2) ? v23 : v01;
            if (n < 4) sm.pp[st & 1][w][m0 + n] = vv;
        }
        __syncthreads();
        p ^= 1;
    }

    // ---------------- final output column (pred from h_255 -> es -> col 223) ----------------
    if (w == 0 && lane < 16) {
        const int par = (kSteps - 1) & 1;  // = 0
        float pr = ((sm.pp[par][0][lane] + sm.pp[par][1][lane]) +
                    (sm.pp[par][2][lane] + sm.pp[par][3][lane])) + bdv;
        es = av * pr + (1.0f - av) * es;
        out[(size_t)(b0 + lane) * kOut + (kOut - 1)] = es;
    }
}

}  // namespace

extern "C" void kernel_launch(void* const* d_in, const int* in_sizes, int n_in,
                              void* d_out, int out_size, void* d_ws, size_t ws_size,
                              hipStream_t stream) {
    const float* inputs = (const float*)d_in[0];
    const float* Wx     = (const float*)d_in[1];
    const float* Wh     = (const float*)d_in[2];
    const float* bias   = (const float*)d_in[3];
    const float* Wd     = (const float*)d_in[4];
    const float* bd     = (const float*)d_in[5];
    const float* alpha  = (const float*)d_in[6];
    // d_in[7] = lags (compile-time constant 32 here)

    arx_rnn_es_kernel<<<kB / kMT, kThreads, 0, stream>>>(
        inputs, Wx, Wh, bias, Wd, bd, alpha, (float*)d_out);
}

// Round 5
// 267.471 us; speedup vs baseline: 5.1657x; 1.0628x over previous
//
#include <hip/hip_runtime.h>

namespace {

constexpr int kB = 4096;
constexpr int kT = 256;
constexpr int kLags = 32;
constexpr int kH = 128;
constexpr int kSteps = 255;   // 32 warmup + 223 AR steps
constexpr int kOut = 224;     // kT - kLags
constexpr int kMT = 16;       // batch rows per block
constexpr int kThreads = 256; // 4 waves; wave w owns cols 32w..32w+31
constexpr int kHS = 136;      // bf16 row stride: 272 B, 16B-aligned (R2-measured benign banks)

typedef __attribute__((ext_vector_type(8))) short short8;
typedef __attribute__((ext_vector_type(4))) float f32x4;

struct __align__(16) SMem {
    unsigned short hhi[2][kMT][kHS];  // h high bf16, double-buffered, A-frag-ready
    unsigned short hlo[2][kMT][kHS];  // h low  bf16
    float x0T[kT][kMT];               // feature 0, transposed [t][m]
    float x1wT[kLags][kMT];           // feature 1 warmup, transposed
};

__device__ __forceinline__ unsigned short bf16_rne(float f) {
    unsigned u = __builtin_bit_cast(unsigned, f);
    u += 0x7FFFu + ((u >> 16) & 1u);
    return (unsigned short)(u >> 16);
}
__device__ __forceinline__ float bf16_f32(unsigned short h) {
    unsigned u = ((unsigned)h) << 16;
    return __builtin_bit_cast(float, u);
}
// tanh(z) given z2 = 2*z   (the *2 is folded into the weights, exact)
__device__ __forceinline__ float tanh_from_2z(float z2) {
    float e = __expf(z2);
    return fmaf(-2.0f, __builtin_amdgcn_rcpf(e + 1.0f), 1.0f);
}

__global__ __launch_bounds__(kThreads)
void arx_rnn_es_kernel(const float* __restrict__ inputs,
                       const float* __restrict__ Wx,
                       const float* __restrict__ Wh,
                       const float* __restrict__ bias,
                       const float* __restrict__ Wd,
                       const float* __restrict__ bd,
                       const float* __restrict__ alpha,
                       float* __restrict__ out) {
    __shared__ SMem sm;
    const int tid  = threadIdx.x;
    const int b0   = blockIdx.x * kMT;
    const int lane = tid & 63;
    const int w    = tid >> 6;        // wave 0..3
    const int n    = lane & 15;
    const int q    = lane >> 4;       // quad
    const int m0   = 4 * q;           // C-rows m0..m0+3

    // ---------------- one-time staging ----------------
    for (int idx = tid; idx < kMT * kT; idx += kThreads) {
        const int mm = idx >> 8;
        const int t  = idx & 255;
        float2 v = ((const float2*)inputs)[(size_t)(b0 + mm) * kT + t];
        sm.x0T[t][mm] = v.x;
        if (t < kLags) sm.x1wT[t][mm] = v.y;
    }
    for (int idx = tid; idx < kMT * kHS; idx += kThreads) {
        ((unsigned short*)sm.hhi[0])[idx] = 0;
        ((unsigned short*)sm.hlo[0])[idx] = 0;
    }

    // per-lane column constants (2 tiles: cols col0, col0+16). All z-path
    // constants pre-scaled by 2 (tanh(z) computed from 2z).
    const int col0 = w * 32 + n;
    float sb2[2], swx0[2], swx1[2], sbp[2];
    const float av  = fminf(fmaxf(alpha[0], 0.0f), 1.0f);
    const float bdv = bd[0];
    float wx1u[2];   // unscaled wx1 (for the fold)
#pragma unroll
    for (int t = 0; t < 2; ++t) {
        const int col = col0 + t * 16;
        const float bc  = bias[col];
        const float w0  = Wx[col];
        const float w1  = Wx[kH + col];
        wx1u[t] = w1;
        sb2[t]  = 2.0f * bc;
        swx0[t] = 2.0f * w0;
        swx1[t] = 2.0f * w1;
        sbp[t]  = 2.0f * (bc + bdv * w1);   // folded bias for AR steps
    }
    __syncthreads();

    int p = 0;

    // ================= warmup: st = 0..31 (unfolded 2*Wh, real x1) =================
    {
        short8 whh[2][4], whl[2][4];
#pragma unroll
        for (int t = 0; t < 2; ++t) {
            const int col = col0 + t * 16;
#pragma unroll
            for (int c = 0; c < 4; ++c) {
#pragma unroll
                for (int j = 0; j < 8; ++j) {
                    const int k = c * 32 + q * 8 + j;
                    float wv = 2.0f * Wh[(size_t)k * kH + col];
                    unsigned short hi = bf16_rne(wv);
                    whh[t][c][j] = (short)hi;
                    whl[t][c][j] = (short)bf16_rne(wv - bf16_f32(hi));
                }
            }
        }

#pragma unroll 1
        for (int st = 0; st < kLags; ++st) {
            f32x4 x0v = *(const f32x4*)&sm.x0T[st][m0];
            f32x4 x1v = *(const f32x4*)&sm.x1wT[st][m0];

            f32x4 A0[2], A1[2], A2[2];
#pragma unroll
            for (int t = 0; t < 2; ++t) { A0[t] = {0,0,0,0}; A1[t] = {0,0,0,0}; A2[t] = {0,0,0,0}; }
#pragma unroll
            for (int c = 0; c < 4; ++c) {
                short8 ah = *(const short8*)&sm.hhi[p][n][c * 32 + 8 * q];
                short8 al = *(const short8*)&sm.hlo[p][n][c * 32 + 8 * q];
#pragma unroll
                for (int t = 0; t < 2; ++t) {
                    A0[t] = __builtin_amdgcn_mfma_f32_16x16x32_bf16(ah, whh[t][c], A0[t], 0, 0, 0);
                    A1[t] = __builtin_amdgcn_mfma_f32_16x16x32_bf16(ah, whl[t][c], A1[t], 0, 0, 0);
                    A2[t] = __builtin_amdgcn_mfma_f32_16x16x32_bf16(al, whh[t][c], A2[t], 0, 0, 0);
                }
            }

            unsigned short his[2][4], los[2][4];
#pragma unroll
            for (int t = 0; t < 2; ++t) {
                f32x4 acc = (A0[t] + A1[t]) + A2[t];
#pragma unroll
                for (int r = 0; r < 4; ++r) {
                    float z2 = acc[r] + sb2[t] + x0v[r] * swx0[t] + x1v[r] * swx1[t];
                    float hf = tanh_from_2z(z2);
                    unsigned short hi = bf16_rne(hf);
                    his[t][r] = hi;
                    los[t][r] = bf16_rne(hf - bf16_f32(hi));
                }
            }
#pragma unroll
            for (int t = 0; t < 2; ++t) {
                const int col = col0 + t * 16;
#pragma unroll
                for (int r = 0; r < 4; ++r) {
                    sm.hhi[1 - p][m0 + r][col] = his[t][r];
                    sm.hlo[1 - p][m0 + r][col] = los[t][r];
                }
            }
            __syncthreads();
            p ^= 1;
        }
    }

    // ---- build folded weights 2*(Wh + Wd*wx1^T) and Wd B-frag (all-col replicate)
    short8 fhh[2][4], fhl[2][4], dh[4];
#pragma unroll
    for (int t = 0; t < 2; ++t) {
        const int col = col0 + t * 16;
#pragma unroll
        for (int c = 0; c < 4; ++c) {
#pragma unroll
            for (int j = 0; j < 8; ++j) {
                const int k = c * 32 + q * 8 + j;
                float wv = 2.0f * fmaf(Wd[k], wx1u[t], Wh[(size_t)k * kH + col]);
                unsigned short hi = bf16_rne(wv);
                fhh[t][c][j] = (short)hi;
                fhl[t][c][j] = (short)bf16_rne(wv - bf16_f32(hi));
                if (t == 0) dh[c][j] = (short)bf16_rne(Wd[k]);  // same for every col
            }
        }
    }

    f32x4 es = {0.f, 0.f, 0.f, 0.f};  // live in (w==0, n==0) lanes, rows m0..m0+3

    // ================= AR: st = 32..254 (pred folded; pred via MFMA vs Wd) =========
#pragma unroll 1
    for (int st = kLags; st < kSteps; ++st) {
        f32x4 x0v = *(const f32x4*)&sm.x0T[st][m0];

        f32x4 A0[2], A1[2], A2[2];
        f32x4 P0 = {0,0,0,0}, P1 = {0,0,0,0};
#pragma unroll
        for (int t = 0; t < 2; ++t) { A0[t] = {0,0,0,0}; A1[t] = {0,0,0,0}; A2[t] = {0,0,0,0}; }
#pragma unroll
        for (int c = 0; c < 4; ++c) {
            short8 ah = *(const short8*)&sm.hhi[p][n][c * 32 + 8 * q];
            short8 al = *(const short8*)&sm.hlo[p][n][c * 32 + 8 * q];
#pragma unroll
            for (int t = 0; t < 2; ++t) {
                A0[t] = __builtin_amdgcn_mfma_f32_16x16x32_bf16(ah, fhh[t][c], A0[t], 0, 0, 0);
                A1[t] = __builtin_amdgcn_mfma_f32_16x16x32_bf16(ah, fhl[t][c], A1[t], 0, 0, 0);
                A2[t] = __builtin_amdgcn_mfma_f32_16x16x32_bf16(al, fhh[t][c], A2[t], 0, 0, 0);
            }
            // pred_{st} = h_st . Wd  (reuses the A-frags already in registers)
            P0 = __builtin_amdgcn_mfma_f32_16x16x32_bf16(ah, dh[c], P0, 0, 0, 0);
            P1 = __builtin_amdgcn_mfma_f32_16x16x32_bf16(al, dh[c], P1, 0, 0, 0);
        }

        // ES stream: D of the pred-MFMA has pred in every col; lanes n==0 own rows.
        if (w == 0 && n == 0) {
            f32x4 pr = P0 + P1;
#pragma unroll
            for (int r = 0; r < 4; ++r) {
                float pv = pr[r] + bdv;
                es[r] = (st == kLags) ? pv : (av * pv + (1.0f - av) * es[r]);
                out[(size_t)(b0 + m0 + r) * kOut + (st - kLags)] = es[r];
            }
        }

        unsigned short his[2][4], los[2][4];
#pragma unroll
        for (int t = 0; t < 2; ++t) {
            f32x4 acc = (A0[t] + A1[t]) + A2[t];
#pragma unroll
            for (int r = 0; r < 4; ++r) {
                float z2 = acc[r] + sbp[t] + x0v[r] * swx0[t];
                float hf = tanh_from_2z(z2);
                unsigned short hi = bf16_rne(hf);
                his[t][r] = hi;
                los[t][r] = bf16_rne(hf - bf16_f32(hi));
            }
        }
#pragma unroll
        for (int t = 0; t < 2; ++t) {
            const int col = col0 + t * 16;
#pragma unroll
            for (int r = 0; r < 4; ++r) {
                sm.hhi[1 - p][m0 + r][col] = his[t][r];
                sm.hlo[1 - p][m0 + r][col] = los[t][r];
            }
        }
        __syncthreads();
        p ^= 1;
    }

    // ================= tail: pred from h_255 -> es -> col 223 =====================
    {
        f32x4 P0 = {0,0,0,0}, P1 = {0,0,0,0};
#pragma unroll
        for (int c = 0; c < 4; ++c) {
            short8 ah = *(const short8*)&sm.hhi[p][n][c * 32 + 8 * q];
            short8 al = *(const short8*)&sm.hlo[p][n][c * 32 + 8 * q];
            P0 = __builtin_amdgcn_mfma_f32_16x16x32_bf16(ah, dh[c], P0, 0, 0, 0);
            P1 = __builtin_amdgcn_mfma_f32_16x16x32_bf16(al, dh[c], P1, 0, 0, 0);
        }
        if (w == 0 && n == 0) {
            f32x4 pr = P0 + P1;
#pragma unroll
            for (int r = 0; r < 4; ++r) {
                float pv = pr[r] + bdv;
                es[r] = av * pv + (1.0f - av) * es[r];
                out[(size_t)(b0 + m0 + r) * kOut + (kOut - 1)] = es[r];
            }
        }
    }
}

}  // namespace

extern "C" void kernel_launch(void* const* d_in, const int* in_sizes, int n_in,
                              void* d_out, int out_size, void* d_ws, size_t ws_size,
                              hipStream_t stream) {
    const float* inputs = (const float*)d_in[0];
    const float* Wx     = (const float*)d_in[1];
    const float* Wh     = (const float*)d_in[2];
    const float* bias   = (const float*)d_in[3];
    const float* Wd     = (const float*)d_in[4];
    const float* bd     = (const float*)d_in[5];
    const float* alpha  = (const float*)d_in[6];
    // d_in[7] = lags (compile-time constant 32 here)

    arx_rnn_es_kernel<<<kB / kMT, kThreads, 0, stream>>>(
        inputs, Wx, Wh, bias, Wd, bd, alpha, (float*)d_out);
}

// Round 6
// 262.746 us; speedup vs baseline: 5.2586x; 1.0180x over previous
//
#include <hip/hip_runtime.h>

namespace {

constexpr int kB = 4096;
constexpr int kT = 256;
constexpr int kLags = 32;
constexpr int kH = 128;
constexpr int kSteps = 255;   // 32 warmup + 223 AR steps
constexpr int kOut = 224;     // kT - kLags
constexpr int kMT = 16;       // batch rows per block
constexpr int kThreads = 256; // 4 waves; wave w owns outcols 32w..32w+31
constexpr int kHS = 136;      // bf16 row stride: 272 B (measured-benign banks)

typedef __attribute__((ext_vector_type(8))) short short8;
typedef __attribute__((ext_vector_type(4))) float f32x4;

struct __align__(16) SMem {
    unsigned short hhi[2][kMT][kHS];  // h high bf16, [buf][batch][col]
    unsigned short hlo[2][kMT][kHS];  // h low  bf16
    float x0T[kT][kMT];               // feature 0, transposed [t][batch]
    float x1wT[kLags][kMT];           // feature 1 warmup, transposed
};

__device__ __forceinline__ unsigned short bf16_rne(float f) {
    unsigned u = __builtin_bit_cast(unsigned, f);
    u += 0x7FFFu + ((u >> 16) & 1u);
    return (unsigned short)(u >> 16);
}
__device__ __forceinline__ float bf16_f32(unsigned short h) {
    unsigned u = ((unsigned)h) << 16;
    return __builtin_bit_cast(float, u);
}
// tanh(z) given z2 = 2*z (the *2 folded into weights/consts, exact)
__device__ __forceinline__ float tanh_from_2z(float z2) {
    float e = __expf(z2);
    return fmaf(-2.0f, __builtin_amdgcn_rcpf(e + 1.0f), 1.0f);
}

__global__ __launch_bounds__(kThreads)
void arx_rnn_es_kernel(const float* __restrict__ inputs,
                       const float* __restrict__ Wx,
                       const float* __restrict__ Wh,
                       const float* __restrict__ bias,
                       const float* __restrict__ Wd,
                       const float* __restrict__ bd,
                       const float* __restrict__ alpha,
                       float* __restrict__ out) {
    __shared__ SMem sm;
    const int tid  = threadIdx.x;
    const int b0   = blockIdx.x * kMT;
    const int lane = tid & 63;
    const int w    = tid >> 6;        // wave 0..3
    const int n    = lane & 15;       // batch row (B-frag col & C col)
    const int q    = lane >> 4;       // quad: C rows 4q..4q+3 (= outcols)

    // ---------------- one-time staging ----------------
    for (int idx = tid; idx < kMT * kT; idx += kThreads) {
        const int mm = idx >> 8;
        const int t  = idx & 255;
        float2 v = ((const float2*)inputs)[(size_t)(b0 + mm) * kT + t];
        sm.x0T[t][mm] = v.x;
        if (t < kLags) sm.x1wT[t][mm] = v.y;
    }
    for (int idx = tid; idx < kMT * kHS; idx += kThreads) {
        ((unsigned short*)sm.hhi[0])[idx] = 0;
        ((unsigned short*)sm.hlo[0])[idx] = 0;
    }

    const float av  = fminf(fmaxf(alpha[0], 0.0f), 1.0f);
    const float bdv = bd[0];

    // ---- epilogue constants: this lane's outcols colE = 32w + 16t + 4q + r ----
    float sb2[2][4], swx0[2][4], swx1e[2][4], sbp[2][4];
#pragma unroll
    for (int t = 0; t < 2; ++t) {
#pragma unroll
        for (int r = 0; r < 4; ++r) {
            const int colE = w * 32 + t * 16 + q * 4 + r;
            const float bc = bias[colE];
            const float w0 = Wx[colE];
            const float w1 = Wx[kH + colE];
            sb2[t][r]   = 2.0f * bc;
            swx0[t][r]  = 2.0f * w0;
            swx1e[t][r] = 2.0f * w1;
            sbp[t][r]   = 2.0f * (bc + bdv * w1);   // folded bias for AR steps
        }
    }
    __syncthreads();

    int p = 0;

    // ================= warmup: st = 0..31 (unfolded 2*Wh, real x1) =================
    {
        // A-operand weight frags: lane holds W2[k=8q+j][col_w = 32w+16t+n]
        short8 whh[2][4], whl[2][4];
#pragma unroll
        for (int t = 0; t < 2; ++t) {
            const int colw = w * 32 + t * 16 + n;
#pragma unroll
            for (int c = 0; c < 4; ++c) {
#pragma unroll
                for (int j = 0; j < 8; ++j) {
                    const int k = c * 32 + q * 8 + j;
                    float wv = 2.0f * Wh[(size_t)k * kH + colw];
                    unsigned short hi = bf16_rne(wv);
                    whh[t][c][j] = (short)hi;
                    whl[t][c][j] = (short)bf16_rne(wv - bf16_f32(hi));
                }
            }
        }

#pragma unroll 1
        for (int st = 0; st < kLags; ++st) {
            const float x0s = sm.x0T[st][n];
            const float x1s = sm.x1wT[st][n];

            f32x4 A0[2], A1[2], A2[2];
#pragma unroll
            for (int t = 0; t < 2; ++t) {
                A0[t] = *(const f32x4*)&sb2[t][0];   // bias pre-loaded into acc
                A1[t] = {0, 0, 0, 0};
                A2[t] = {0, 0, 0, 0};
            }
#pragma unroll
            for (int c = 0; c < 4; ++c) {
                short8 bh = *(const short8*)&sm.hhi[p][n][c * 32 + 8 * q];
                short8 bl = *(const short8*)&sm.hlo[p][n][c * 32 + 8 * q];
#pragma unroll
                for (int t = 0; t < 2; ++t) {
                    A0[t] = __builtin_amdgcn_mfma_f32_16x16x32_bf16(whh[t][c], bh, A0[t], 0, 0, 0);
                    A1[t] = __builtin_amdgcn_mfma_f32_16x16x32_bf16(whl[t][c], bh, A1[t], 0, 0, 0);
                    A2[t] = __builtin_amdgcn_mfma_f32_16x16x32_bf16(whh[t][c], bl, A2[t], 0, 0, 0);
                }
            }

#pragma unroll
            for (int t = 0; t < 2; ++t) {
                f32x4 acc = (A0[t] + A1[t]) + A2[t];
                unsigned rb[4], db[4];
#pragma unroll
                for (int r = 0; r < 4; ++r) {
                    float z2 = acc[r] + x0s * swx0[t][r] + x1s * swx1e[t][r];
                    float hf = tanh_from_2z(z2);
                    unsigned u = __builtin_bit_cast(unsigned, hf);
                    rb[r] = (u + (0x7FFFu + ((u >> 16) & 1u))) & 0xFFFF0000u;
                    float d = hf - __builtin_bit_cast(float, rb[r]);
                    db[r] = __builtin_bit_cast(unsigned, d);   // truncated lo in top 16
                }
                uint2 uh, ul;
                uh.x = __builtin_amdgcn_perm(rb[1], rb[0], 0x07060302u);
                uh.y = __builtin_amdgcn_perm(rb[3], rb[2], 0x07060302u);
                ul.x = __builtin_amdgcn_perm(db[1], db[0], 0x07060302u);
                ul.y = __builtin_amdgcn_perm(db[3], db[2], 0x07060302u);
                const int wcol = w * 32 + t * 16 + q * 4;
                *(uint2*)&sm.hhi[1 - p][n][wcol] = uh;
                *(uint2*)&sm.hlo[1 - p][n][wcol] = ul;
            }
            __syncthreads();
            p ^= 1;
        }
    }

    // ---- folded AR weights 2*(Wh + Wd*wx1^T) and Wd-replicated pred frag ----
    short8 fhh[2][4], fhl[2][4], dh[4];
#pragma unroll
    for (int t = 0; t < 2; ++t) {
        const int colw = w * 32 + t * 16 + n;
        const float wx1w = Wx[kH + colw];
#pragma unroll
        for (int c = 0; c < 4; ++c) {
#pragma unroll
            for (int j = 0; j < 8; ++j) {
                const int k = c * 32 + q * 8 + j;
                float wv = 2.0f * fmaf(Wd[k], wx1w, Wh[(size_t)k * kH + colw]);
                unsigned short hi = bf16_rne(wv);
                fhh[t][c][j] = (short)hi;
                fhl[t][c][j] = (short)bf16_rne(wv - bf16_f32(hi));
                if (t == 0) dh[c][j] = (short)bf16_rne(Wd[k]);  // k-only: same all rows
            }
        }
    }

    float es = 0.0f;   // wave 0, lanes 0..15: es for batch row n

    // ================= AR: st = 32..254 (pred folded; pred via MFMA on w0) =========
#pragma unroll 1
    for (int st = kLags; st < kSteps; ++st) {
        const float x0s = sm.x0T[st][n];

        f32x4 A0[2], A1[2], A2[2];
        f32x4 P0 = {0, 0, 0, 0}, P1 = {0, 0, 0, 0};
#pragma unroll
        for (int t = 0; t < 2; ++t) {
            A0[t] = *(const f32x4*)&sbp[t][0];
            A1[t] = {0, 0, 0, 0};
            A2[t] = {0, 0, 0, 0};
        }
#pragma unroll
        for (int c = 0; c < 4; ++c) {
            short8 bh = *(const short8*)&sm.hhi[p][n][c * 32 + 8 * q];
            short8 bl = *(const short8*)&sm.hlo[p][n][c * 32 + 8 * q];
#pragma unroll
            for (int t = 0; t < 2; ++t) {
                A0[t] = __builtin_amdgcn_mfma_f32_16x16x32_bf16(fhh[t][c], bh, A0[t], 0, 0, 0);
                A1[t] = __builtin_amdgcn_mfma_f32_16x16x32_bf16(fhl[t][c], bh, A1[t], 0, 0, 0);
                A2[t] = __builtin_amdgcn_mfma_f32_16x16x32_bf16(fhh[t][c], bl, A2[t], 0, 0, 0);
            }
            if (w == 0) {   // pred_{st-1} = h_{st-1} . Wd (every D row holds it)
                P0 = __builtin_amdgcn_mfma_f32_16x16x32_bf16(dh[c], bh, P0, 0, 0, 0);
                P1 = __builtin_amdgcn_mfma_f32_16x16x32_bf16(dh[c], bl, P1, 0, 0, 0);
            }
        }

        // ES stream: scalar per batch row, lanes 0..15 of wave 0
        if (w == 0 && q == 0) {
            float pv = (P0[0] + P1[0]) + bdv;
            es = (st == kLags) ? pv : fmaf(av, pv - es, es);
            out[(size_t)(b0 + n) * kOut + (st - kLags)] = es;
        }

#pragma unroll
        for (int t = 0; t < 2; ++t) {
            f32x4 acc = (A0[t] + A1[t]) + A2[t];
            unsigned rb[4], db[4];
#pragma unroll
            for (int r = 0; r < 4; ++r) {
                float z2 = acc[r] + x0s * swx0[t][r];
                float hf = tanh_from_2z(z2);
                unsigned u = __builtin_bit_cast(unsigned, hf);
                rb[r] = (u + (0x7FFFu + ((u >> 16) & 1u))) & 0xFFFF0000u;
                float d = hf - __builtin_bit_cast(float, rb[r]);
                db[r] = __builtin_bit_cast(unsigned, d);
            }
            uint2 uh, ul;
            uh.x = __builtin_amdgcn_perm(rb[1], rb[0], 0x07060302u);
            uh.y = __builtin_amdgcn_perm(rb[3], rb[2], 0x07060302u);
            ul.x = __builtin_amdgcn_perm(db[1], db[0], 0x07060302u);
            ul.y = __builtin_amdgcn_perm(db[3], db[2], 0x07060302u);
            const int wcol = w * 32 + t * 16 + q * 4;
            *(uint2*)&sm.hhi[1 - p][n][wcol] = uh;
            *(uint2*)&sm.hlo[1 - p][n][wcol] = ul;
        }
        __syncthreads();
        p ^= 1;
    }

    // ================= tail: pred from h_254 -> es -> col 223 =====================
    if (w == 0) {
        f32x4 P0 = {0, 0, 0, 0}, P1 = {0, 0, 0, 0};
#pragma unroll
        for (int c = 0; c < 4; ++c) {
            short8 bh = *(const short8*)&sm.hhi[p][n][c * 32 + 8 * q];
            short8 bl = *(const short8*)&sm.hlo[p][n][c * 32 + 8 * q];
            P0 = __builtin_amdgcn_mfma_f32_16x16x32_bf16(dh[c], bh, P0, 0, 0, 0);
            P1 = __builtin_amdgcn_mfma_f32_16x16x32_bf16(dh[c], bl, P1, 0, 0, 0);
        }
        if (q == 0) {
            float pv = (P0[0] + P1[0]) + bdv;
            es = fmaf(av, pv - es, es);
            out[(size_t)(b0 + n) * kOut + (kOut - 1)] = es;
        }
    }
}

}  // namespace

extern "C" void kernel_launch(void* const* d_in, const int* in_sizes, int n_in,
                              void* d_out, int out_size, void* d_ws, size_t ws_size,
                              hipStream_t stream) {
    const float* inputs = (const float*)d_in[0];
    const float* Wx     = (const float*)d_in[1];
    const float* Wh     = (const float*)d_in[2];
    const float* bias   = (const float*)d_in[3];
    const float* Wd     = (const float*)d_in[4];
    const float* bd     = (const float*)d_in[5];
    const float* alpha  = (const float*)d_in[6];
    // d_in[7] = lags (compile-time constant 32 here)

    arx_rnn_es_kernel<<<kB / kMT, kThreads, 0, stream>>>(
        inputs, Wx, Wh, bias, Wd, bd, alpha, (float*)d_out);
}

// Round 7
// 261.965 us; speedup vs baseline: 5.2743x; 1.0030x over previous
//
#include <hip/hip_runtime.h>

namespace {

constexpr int kB = 4096;
constexpr int kT = 256;
constexpr int kLags = 32;
constexpr int kH = 128;
constexpr int kSteps = 255;   // 32 warmup + 223 AR steps
constexpr int kOut = 224;     // kT - kLags
constexpr int kMT = 16;       // batch rows per block
constexpr int kThreads = 256; // 4 waves; wave w owns outcols 32w..32w+31
constexpr int kHS = 136;      // bf16 row stride: 272 B (measured-benign banks)
constexpr int kOS = 225;      // obuf row stride (odd => scatter writes spread banks)

typedef __attribute__((ext_vector_type(8))) short short8;
typedef __attribute__((ext_vector_type(4))) float f32x4;

struct __align__(16) SMem {
    unsigned short hhi[2][kMT][kHS];  // h high bf16, [buf][batch][col]
    unsigned short hlo[2][kMT][kHS];  // h low  bf16
    float x0T[kT][kMT];               // feature 0, transposed [t][batch]
    float x1wT[kLags][kMT];           // feature 1 warmup, transposed
    float obuf[kMT][kOS];             // ES output staging (flushed to HBM at end)
};

__device__ __forceinline__ unsigned short bf16_rne(float f) {
    unsigned u = __builtin_bit_cast(unsigned, f);
    u += 0x7FFFu + ((u >> 16) & 1u);
    return (unsigned short)(u >> 16);
}
__device__ __forceinline__ float bf16_f32(unsigned short h) {
    unsigned u = ((unsigned)h) << 16;
    return __builtin_bit_cast(float, u);
}
// tanh(z) given z2 = 2*z (the *2 folded into weights/consts, exact)
__device__ __forceinline__ float tanh_from_2z(float z2) {
    float e = __expf(z2);
    return fmaf(-2.0f, __builtin_amdgcn_rcpf(e + 1.0f), 1.0f);
}

__global__ __launch_bounds__(kThreads)
void arx_rnn_es_kernel(const float* __restrict__ inputs,
                       const float* __restrict__ Wx,
                       const float* __restrict__ Wh,
                       const float* __restrict__ bias,
                       const float* __restrict__ Wd,
                       const float* __restrict__ bd,
                       const float* __restrict__ alpha,
                       float* __restrict__ out) {
    __shared__ SMem sm;
    const int tid  = threadIdx.x;
    const int b0   = blockIdx.x * kMT;
    const int lane = tid & 63;
    const int w    = tid >> 6;        // wave 0..3
    const int n    = lane & 15;       // batch row (B-frag col & C col)
    const int q    = lane >> 4;       // quad: C rows 4q..4q+3 (= outcols)

    // ---------------- one-time staging ----------------
    for (int idx = tid; idx < kMT * kT; idx += kThreads) {
        const int mm = idx >> 8;
        const int t  = idx & 255;
        float2 v = ((const float2*)inputs)[(size_t)(b0 + mm) * kT + t];
        sm.x0T[t][mm] = v.x;
        if (t < kLags) sm.x1wT[t][mm] = v.y;
    }
    for (int idx = tid; idx < kMT * kHS; idx += kThreads) {
        ((unsigned short*)sm.hhi[0])[idx] = 0;
        ((unsigned short*)sm.hlo[0])[idx] = 0;
    }

    const float av  = fminf(fmaxf(alpha[0], 0.0f), 1.0f);
    const float bdv = bd[0];

    // ---- epilogue constants: this lane's outcols colE = 32w + 16t + 4q + r ----
    float sb2[2][4], swx0[2][4], swx1e[2][4], sbp[2][4];
#pragma unroll
    for (int t = 0; t < 2; ++t) {
#pragma unroll
        for (int r = 0; r < 4; ++r) {
            const int colE = w * 32 + t * 16 + q * 4 + r;
            const float bc = bias[colE];
            const float w0 = Wx[colE];
            const float w1 = Wx[kH + colE];
            sb2[t][r]   = 2.0f * bc;
            swx0[t][r]  = 2.0f * w0;
            swx1e[t][r] = 2.0f * w1;
            sbp[t][r]   = 2.0f * (bc + bdv * w1);   // folded bias for AR steps
        }
    }
    __syncthreads();

    int p = 0;

    // ================= warmup: st = 0..31 (unfolded 2*Wh, real x1) =================
    {
        // A-operand weight frags: lane holds W2[k=8q+j][col_w = 32w+16t+n]
        short8 whh[2][4], whl[2][4];
#pragma unroll
        for (int t = 0; t < 2; ++t) {
            const int colw = w * 32 + t * 16 + n;
#pragma unroll
            for (int c = 0; c < 4; ++c) {
#pragma unroll
                for (int j = 0; j < 8; ++j) {
                    const int k = c * 32 + q * 8 + j;
                    float wv = 2.0f * Wh[(size_t)k * kH + colw];
                    unsigned short hi = bf16_rne(wv);
                    whh[t][c][j] = (short)hi;
                    whl[t][c][j] = (short)bf16_rne(wv - bf16_f32(hi));
                }
            }
        }

#pragma unroll 1
        for (int st = 0; st < kLags; ++st) {
            const float x0s = sm.x0T[st][n];
            const float x1s = sm.x1wT[st][n];

            f32x4 A0[2], A1[2], A2[2];
#pragma unroll
            for (int t = 0; t < 2; ++t) {
                A0[t] = *(const f32x4*)&sb2[t][0];   // bias pre-loaded into acc
                A1[t] = {0, 0, 0, 0};
                A2[t] = {0, 0, 0, 0};
            }
#pragma unroll
            for (int c = 0; c < 4; ++c) {
                short8 bh = *(const short8*)&sm.hhi[p][n][c * 32 + 8 * q];
                short8 bl = *(const short8*)&sm.hlo[p][n][c * 32 + 8 * q];
#pragma unroll
                for (int t = 0; t < 2; ++t) {
                    A0[t] = __builtin_amdgcn_mfma_f32_16x16x32_bf16(whh[t][c], bh, A0[t], 0, 0, 0);
                    A1[t] = __builtin_amdgcn_mfma_f32_16x16x32_bf16(whl[t][c], bh, A1[t], 0, 0, 0);
                    A2[t] = __builtin_amdgcn_mfma_f32_16x16x32_bf16(whh[t][c], bl, A2[t], 0, 0, 0);
                }
            }

#pragma unroll
            for (int t = 0; t < 2; ++t) {
                f32x4 acc = (A0[t] + A1[t]) + A2[t];
                unsigned rb[4], db[4];
#pragma unroll
                for (int r = 0; r < 4; ++r) {
                    float z2 = acc[r] + x0s * swx0[t][r] + x1s * swx1e[t][r];
                    float hf = tanh_from_2z(z2);
                    unsigned u = __builtin_bit_cast(unsigned, hf);
                    rb[r] = (u + (0x7FFFu + ((u >> 16) & 1u))) & 0xFFFF0000u;
                    float d = hf - __builtin_bit_cast(float, rb[r]);
                    db[r] = __builtin_bit_cast(unsigned, d);   // truncated lo in top 16
                }
                uint2 uh, ul;
                uh.x = __builtin_amdgcn_perm(rb[1], rb[0], 0x07060302u);
                uh.y = __builtin_amdgcn_perm(rb[3], rb[2], 0x07060302u);
                ul.x = __builtin_amdgcn_perm(db[1], db[0], 0x07060302u);
                ul.y = __builtin_amdgcn_perm(db[3], db[2], 0x07060302u);
                const int wcol = w * 32 + t * 16 + q * 4;
                *(uint2*)&sm.hhi[1 - p][n][wcol] = uh;
                *(uint2*)&sm.hlo[1 - p][n][wcol] = ul;
            }
            __syncthreads();
            p ^= 1;
        }
    }

    // ---- folded AR weights 2*(Wh + Wd*wx1^T) and Wd-replicated pred frag ----
    short8 fhh[2][4], fhl[2][4], dh[4];
#pragma unroll
    for (int t = 0; t < 2; ++t) {
        const int colw = w * 32 + t * 16 + n;
        const float wx1w = Wx[kH + colw];
#pragma unroll
        for (int c = 0; c < 4; ++c) {
#pragma unroll
            for (int j = 0; j < 8; ++j) {
                const int k = c * 32 + q * 8 + j;
                float wv = 2.0f * fmaf(Wd[k], wx1w, Wh[(size_t)k * kH + colw]);
                unsigned short hi = bf16_rne(wv);
                fhh[t][c][j] = (short)hi;
                fhl[t][c][j] = (short)bf16_rne(wv - bf16_f32(hi));
                if (t == 0) dh[c][j] = (short)bf16_rne(Wd[k]);  // k-only: same all rows
            }
        }
    }

    float es = 0.0f;   // wave 0, lanes 0..15: es for batch row n

    // ================= AR: st = 32..254 (pred folded; pred via MFMA on w0) =========
#pragma unroll 1
    for (int st = kLags; st < kSteps; ++st) {
        const float x0s = sm.x0T[st][n];

        f32x4 A0[2], A1[2], A2[2];
        f32x4 P0 = {0, 0, 0, 0}, P1 = {0, 0, 0, 0};
#pragma unroll
        for (int t = 0; t < 2; ++t) {
            A0[t] = *(const f32x4*)&sbp[t][0];
            A1[t] = {0, 0, 0, 0};
            A2[t] = {0, 0, 0, 0};
        }
#pragma unroll
        for (int c = 0; c < 4; ++c) {
            short8 bh = *(const short8*)&sm.hhi[p][n][c * 32 + 8 * q];
            short8 bl = *(const short8*)&sm.hlo[p][n][c * 32 + 8 * q];
#pragma unroll
            for (int t = 0; t < 2; ++t) {
                A0[t] = __builtin_amdgcn_mfma_f32_16x16x32_bf16(fhh[t][c], bh, A0[t], 0, 0, 0);
                A1[t] = __builtin_amdgcn_mfma_f32_16x16x32_bf16(fhl[t][c], bh, A1[t], 0, 0, 0);
                A2[t] = __builtin_amdgcn_mfma_f32_16x16x32_bf16(fhh[t][c], bl, A2[t], 0, 0, 0);
            }
            if (w == 0) {   // pred_{st-1} = h_{st-1} . Wd (every D row holds it)
                P0 = __builtin_amdgcn_mfma_f32_16x16x32_bf16(dh[c], bh, P0, 0, 0, 0);
                P1 = __builtin_amdgcn_mfma_f32_16x16x32_bf16(dh[c], bl, P1, 0, 0, 0);
            }
        }

        // ES stream -> LDS staging (global store deferred to kernel end; keeps
        // the vmcnt(0)-drain-before-barrier off the per-step critical path)
        if (w == 0 && q == 0) {
            float pv = (P0[0] + P1[0]) + bdv;
            es = (st == kLags) ? pv : fmaf(av, pv - es, es);
            sm.obuf[n][st - kLags] = es;
        }

#pragma unroll
        for (int t = 0; t < 2; ++t) {
            f32x4 acc = (A0[t] + A1[t]) + A2[t];
            unsigned rb[4], db[4];
#pragma unroll
            for (int r = 0; r < 4; ++r) {
                float z2 = acc[r] + x0s * swx0[t][r];
                float hf = tanh_from_2z(z2);
                unsigned u = __builtin_bit_cast(unsigned, hf);
                rb[r] = (u + (0x7FFFu + ((u >> 16) & 1u))) & 0xFFFF0000u;
                float d = hf - __builtin_bit_cast(float, rb[r]);
                db[r] = __builtin_bit_cast(unsigned, d);
            }
            uint2 uh, ul;
            uh.x = __builtin_amdgcn_perm(rb[1], rb[0], 0x07060302u);
            uh.y = __builtin_amdgcn_perm(rb[3], rb[2], 0x07060302u);
            ul.x = __builtin_amdgcn_perm(db[1], db[0], 0x07060302u);
            ul.y = __builtin_amdgcn_perm(db[3], db[2], 0x07060302u);
            const int wcol = w * 32 + t * 16 + q * 4;
            *(uint2*)&sm.hhi[1 - p][n][wcol] = uh;
            *(uint2*)&sm.hlo[1 - p][n][wcol] = ul;
        }
        __syncthreads();
        p ^= 1;
    }

    // ================= tail: pred from h_254 -> es -> col 223 =====================
    if (w == 0) {
        f32x4 P0 = {0, 0, 0, 0}, P1 = {0, 0, 0, 0};
#pragma unroll
        for (int c = 0; c < 4; ++c) {
            short8 bh = *(const short8*)&sm.hhi[p][n][c * 32 + 8 * q];
            short8 bl = *(const short8*)&sm.hlo[p][n][c * 32 + 8 * q];
            P0 = __builtin_amdgcn_mfma_f32_16x16x32_bf16(dh[c], bh, P0, 0, 0, 0);
            P1 = __builtin_amdgcn_mfma_f32_16x16x32_bf16(dh[c], bl, P1, 0, 0, 0);
        }
        if (q == 0) {
            float pv = (P0[0] + P1[0]) + bdv;
            es = fmaf(av, pv - es, es);
            sm.obuf[n][kOut - 1] = es;
        }
    }

    // ================= flush ES staging buffer to HBM (coalesced) =================
    __syncthreads();
    for (int idx = tid; idx < kMT * kOut; idx += kThreads) {
        const int mm = idx / kOut;
        const int t  = idx - mm * kOut;
        out[(size_t)(b0 + mm) * kOut + t] = sm.obuf[mm][t];
    }
}

}  // namespace

extern "C" void kernel_launch(void* const* d_in, const int* in_sizes, int n_in,
                              void* d_out, int out_size, void* d_ws, size_t ws_size,
                              hipStream_t stream) {
    const float* inputs = (const float*)d_in[0];
    const float* Wx     = (const float*)d_in[1];
    const float* Wh     = (const float*)d_in[2];
    const float* bias   = (const float*)d_in[3];
    const float* Wd     = (const float*)d_in[4];
    const float* bd     = (const float*)d_in[5];
    const float* alpha  = (const float*)d_in[6];
    // d_in[7] = lags (compile-time constant 32 here)

    arx_rnn_es_kernel<<<kB / kMT, kThreads, 0, stream>>>(
        inputs, Wx, Wh, bias, Wd, bd, alpha, (float*)d_out);
}

// Round 8
// 220.542 us; speedup vs baseline: 6.2649x; 1.1878x over previous
//
#include <hip/hip_runtime.h>

namespace {

constexpr int kB = 4096;
constexpr int kT = 256;
constexpr int kLags = 32;
constexpr int kH = 128;
constexpr int kSteps = 255;   // 32 warmup + 223 AR steps
constexpr int kOut = 224;     // kT - kLags
constexpr int kMT = 16;       // batch rows per block
constexpr int kThreads = 512; // 8 waves; wave w owns outcols 16w..16w+15
constexpr int kHS = 136;      // bf16 row stride: 272 B (measured-benign banks)
constexpr int kOS = 225;      // obuf row stride

typedef __attribute__((ext_vector_type(8))) short short8;
typedef __attribute__((ext_vector_type(4))) float f32x4;

struct __align__(16) SMem {
    unsigned short hhi[2][kMT][kHS];  // h high bf16, [buf][batch][col]
    unsigned short hlo[2][kMT][kHS];  // h low  bf16
    float x0T[kT][kMT];               // feature 0, transposed [t][batch]
    float x1wT[kLags][kMT];           // feature 1 warmup, transposed
    float obuf[kMT][kOS];             // ES output staging
};

__device__ __forceinline__ unsigned short bf16_rne(float f) {
    unsigned u = __builtin_bit_cast(unsigned, f);
    u += 0x7FFFu + ((u >> 16) & 1u);
    return (unsigned short)(u >> 16);
}
__device__ __forceinline__ float bf16_f32(unsigned short h) {
    unsigned u = ((unsigned)h) << 16;
    return __builtin_bit_cast(float, u);
}
// tanh(z) given z2 = 2*z (the *2 folded into weights/consts, exact)
__device__ __forceinline__ float tanh_from_2z(float z2) {
    float e = __expf(z2);
    return fmaf(-2.0f, __builtin_amdgcn_rcpf(e + 1.0f), 1.0f);
}

__global__ __launch_bounds__(kThreads, 2)
void arx_rnn_es_kernel(const float* __restrict__ inputs,
                       const float* __restrict__ Wx,
                       const float* __restrict__ Wh,
                       const float* __restrict__ bias,
                       const float* __restrict__ Wd,
                       const float* __restrict__ bd,
                       const float* __restrict__ alpha,
                       float* __restrict__ out) {
    __shared__ SMem sm;
    const int tid  = threadIdx.x;
    const int b0   = blockIdx.x * kMT;
    const int lane = tid & 63;
    const int w    = tid >> 6;        // wave 0..7, owns outcols 16w..16w+15
    const int n    = lane & 15;       // batch row (B-frag col & C col)
    const int q    = lane >> 4;       // quad: C rows 4q..4q+3 (= outcols in tile)

    // ---------------- one-time staging ----------------
    for (int idx = tid; idx < kMT * kT; idx += kThreads) {
        const int mm = idx >> 8;
        const int t  = idx & 255;
        float2 v = ((const float2*)inputs)[(size_t)(b0 + mm) * kT + t];
        sm.x0T[t][mm] = v.x;
        if (t < kLags) sm.x1wT[t][mm] = v.y;
    }
    for (int idx = tid; idx < kMT * kHS; idx += kThreads) {
        ((unsigned short*)sm.hhi[0])[idx] = 0;
        ((unsigned short*)sm.hlo[0])[idx] = 0;
    }

    const float av  = fminf(fmaxf(alpha[0], 0.0f), 1.0f);
    const float bdv = bd[0];

    // ---- epilogue constants: this lane's outcols colE = 16w + 4q + r ----
    float sb2[4], swx0[4], swx1e[4], sbp[4];
#pragma unroll
    for (int r = 0; r < 4; ++r) {
        const int colE = w * 16 + q * 4 + r;
        const float bc = bias[colE];
        const float w0 = Wx[colE];
        const float w1 = Wx[kH + colE];
        sb2[r]   = 2.0f * bc;
        swx0[r]  = 2.0f * w0;
        swx1e[r] = 2.0f * w1;
        sbp[r]   = 2.0f * (bc + bdv * w1);   // folded bias for AR steps
    }
    __syncthreads();

    int p = 0;

    // ================= warmup: st = 0..31 (unfolded 2*Wh, real x1) =================
    {
        // A-operand weight frags: lane holds W2[k = c*32+8q+j][colw = 16w + n]
        short8 whh[4], whl[4];
        {
            const int colw = w * 16 + n;
#pragma unroll
            for (int c = 0; c < 4; ++c) {
#pragma unroll
                for (int j = 0; j < 8; ++j) {
                    const int k = c * 32 + q * 8 + j;
                    float wv = 2.0f * Wh[(size_t)k * kH + colw];
                    unsigned short hi = bf16_rne(wv);
                    whh[c][j] = (short)hi;
                    whl[c][j] = (short)bf16_rne(wv - bf16_f32(hi));
                }
            }
        }

#pragma unroll 1
        for (int st = 0; st < kLags; ++st) {
            const float x0s = sm.x0T[st][n];
            const float x1s = sm.x1wT[st][n];

            f32x4 A = *(const f32x4*)&sb2[0];   // bias preloaded into acc
#pragma unroll
            for (int c = 0; c < 4; ++c) {
                short8 bh = *(const short8*)&sm.hhi[p][n][c * 32 + 8 * q];
                short8 bl = *(const short8*)&sm.hlo[p][n][c * 32 + 8 * q];
                A = __builtin_amdgcn_mfma_f32_16x16x32_bf16(whh[c], bh, A, 0, 0, 0);
                A = __builtin_amdgcn_mfma_f32_16x16x32_bf16(whl[c], bh, A, 0, 0, 0);
                A = __builtin_amdgcn_mfma_f32_16x16x32_bf16(whh[c], bl, A, 0, 0, 0);
            }

            unsigned rb[4], db[4];
#pragma unroll
            for (int r = 0; r < 4; ++r) {
                float z2 = A[r] + x0s * swx0[r] + x1s * swx1e[r];
                float hf = tanh_from_2z(z2);
                unsigned u = __builtin_bit_cast(unsigned, hf);
                rb[r] = (u + (0x7FFFu + ((u >> 16) & 1u))) & 0xFFFF0000u;
                float d = hf - __builtin_bit_cast(float, rb[r]);
                db[r] = __builtin_bit_cast(unsigned, d);   // truncated lo in top 16
            }
            uint2 uh, ul;
            uh.x = __builtin_amdgcn_perm(rb[1], rb[0], 0x07060302u);
            uh.y = __builtin_amdgcn_perm(rb[3], rb[2], 0x07060302u);
            ul.x = __builtin_amdgcn_perm(db[1], db[0], 0x07060302u);
            ul.y = __builtin_amdgcn_perm(db[3], db[2], 0x07060302u);
            const int wcol = w * 16 + q * 4;
            *(uint2*)&sm.hhi[1 - p][n][wcol] = uh;
            *(uint2*)&sm.hlo[1 - p][n][wcol] = ul;

            __syncthreads();
            p ^= 1;
        }
    }

    // ---- folded AR weights 2*(Wh + Wd*wx1^T) and Wd-replicated pred frag ----
    short8 fhh[4], fhl[4], dh[4];
    {
        const int colw = w * 16 + n;
        const float wx1w = Wx[kH + colw];
#pragma unroll
        for (int c = 0; c < 4; ++c) {
#pragma unroll
            for (int j = 0; j < 8; ++j) {
                const int k = c * 32 + q * 8 + j;
                float wv = 2.0f * fmaf(Wd[k], wx1w, Wh[(size_t)k * kH + colw]);
                unsigned short hi = bf16_rne(wv);
                fhh[c][j] = (short)hi;
                fhl[c][j] = (short)bf16_rne(wv - bf16_f32(hi));
                dh[c][j]  = (short)bf16_rne(Wd[k]);  // k-only: same for all rows
            }
        }
    }

    float es = 0.0f;   // wave 0, q==0, lanes n: es for batch row n

    // ================= AR: st = 32..254 (pred folded; pred via MFMA on w0) =========
#pragma unroll 1
    for (int st = kLags; st < kSteps; ++st) {
        const float x0s = sm.x0T[st][n];

        f32x4 A = *(const f32x4*)&sbp[0];
        f32x4 P = {0, 0, 0, 0};
#pragma unroll
        for (int c = 0; c < 4; ++c) {
            short8 bh = *(const short8*)&sm.hhi[p][n][c * 32 + 8 * q];
            short8 bl = *(const short8*)&sm.hlo[p][n][c * 32 + 8 * q];
            A = __builtin_amdgcn_mfma_f32_16x16x32_bf16(fhh[c], bh, A, 0, 0, 0);
            A = __builtin_amdgcn_mfma_f32_16x16x32_bf16(fhl[c], bh, A, 0, 0, 0);
            A = __builtin_amdgcn_mfma_f32_16x16x32_bf16(fhh[c], bl, A, 0, 0, 0);
            if (w == 0) {   // pred_{st} = h_{st} . Wd (every D row holds it)
                P = __builtin_amdgcn_mfma_f32_16x16x32_bf16(dh[c], bh, P, 0, 0, 0);
                P = __builtin_amdgcn_mfma_f32_16x16x32_bf16(dh[c], bl, P, 0, 0, 0);
            }
        }

        // ES stream -> LDS staging; wave 0, q==0 lanes own batch row n
        if (w == 0 && q == 0) {
            float pv = P[0] + bdv;
            es = (st == kLags) ? pv : fmaf(av, pv - es, es);
            sm.obuf[n][st - kLags] = es;
        }

        unsigned rb[4], db[4];
#pragma unroll
        for (int r = 0; r < 4; ++r) {
            float z2 = A[r] + x0s * swx0[r];
            float hf = tanh_from_2z(z2);
            unsigned u = __builtin_bit_cast(unsigned, hf);
            rb[r] = (u + (0x7FFFu + ((u >> 16) & 1u))) & 0xFFFF0000u;
            float d = hf - __builtin_bit_cast(float, rb[r]);
            db[r] = __builtin_bit_cast(unsigned, d);
        }
        uint2 uh, ul;
        uh.x = __builtin_amdgcn_perm(rb[1], rb[0], 0x07060302u);
        uh.y = __builtin_amdgcn_perm(rb[3], rb[2], 0x07060302u);
        ul.x = __builtin_amdgcn_perm(db[1], db[0], 0x07060302u);
        ul.y = __builtin_amdgcn_perm(db[3], db[2], 0x07060302u);
        const int wcol = w * 16 + q * 4;
        *(uint2*)&sm.hhi[1 - p][n][wcol] = uh;
        *(uint2*)&sm.hlo[1 - p][n][wcol] = ul;

        __syncthreads();
        p ^= 1;
    }

    // ================= tail: pred from h_255 -> es -> col 223 =====================
    if (w == 0) {
        f32x4 P = {0, 0, 0, 0};
#pragma unroll
        for (int c = 0; c < 4; ++c) {
            short8 bh = *(const short8*)&sm.hhi[p][n][c * 32 + 8 * q];
            short8 bl = *(const short8*)&sm.hlo[p][n][c * 32 + 8 * q];
            P = __builtin_amdgcn_mfma_f32_16x16x32_bf16(dh[c], bh, P, 0, 0, 0);
            P = __builtin_amdgcn_mfma_f32_16x16x32_bf16(dh[c], bl, P, 0, 0, 0);
        }
        if (q == 0) {
            float pv = P[0] + bdv;
            es = fmaf(av, pv - es, es);
            sm.obuf[n][kOut - 1] = es;
        }
    }

    // ================= flush ES staging buffer to HBM (coalesced) =================
    __syncthreads();
    for (int idx = tid; idx < kMT * kOut; idx += kThreads) {
        const int mm = idx / kOut;
        const int t  = idx - mm * kOut;
        out[(size_t)(b0 + mm) * kOut + t] = sm.obuf[mm][t];
    }
}

}  // namespace

extern "C" void kernel_launch(void* const* d_in, const int* in_sizes, int n_in,
                              void* d_out, int out_size, void* d_ws, size_t ws_size,
                              hipStream_t stream) {
    const float* inputs = (const float*)d_in[0];
    const float* Wx     = (const float*)d_in[1];
    const float* Wh     = (const float*)d_in[2];
    const float* bias   = (const float*)d_in[3];
    const float* Wd     = (const float*)d_in[4];
    const float* bd     = (const float*)d_in[5];
    const float* alpha  = (const float*)d_in[6];
    // d_in[7] = lags (compile-time constant 32 here)

    arx_rnn_es_kernel<<<kB / kMT, kThreads, 0, stream>>>(
        inputs, Wx, Wh, bias, Wd, bd, alpha, (float*)d_out);
}